// Round 6
// baseline (82.047 us; speedup 1.0000x reference)
//
#include <hip/hip_runtime.h>

#define SEQ_LEN 131072
#define D_MODEL 512
#define M_SIZE  1000
#define BETA    0.5f
#define CAP     192          // bucket capacity; mean count ~65, 192 is >15 sigma

typedef float f32x4 __attribute__((ext_vector_type(4)));

// ws layout (bytes)
#define WMT_OFF 0
#define CNT_OFF (2 * 1024 * 1024)
#define BKT_OFF (CNT_OFF + 8192)
#define WS_NEED (BKT_OFF + (size_t)M_SIZE * CAP * 8)

// ---------------------------------------------------------------------------
// K1: transpose W_m [D][M] -> W_mT [M][D] (2 MB). Block (0,0) also zeroes the
// bucket counters (runs every call; harness does not re-poison ws).
// ---------------------------------------------------------------------------
__global__ void transpose_wm_kernel(const float* __restrict__ W_m,
                                    float* __restrict__ W_mT,
                                    int* __restrict__ cnt) {
    if (blockIdx.x == 0 && blockIdx.y == 0) {
        const int tid = threadIdx.y * 32 + threadIdx.x;  // 0..255
        for (int i = tid; i < M_SIZE; i += 256) cnt[i] = 0;
    }
    __shared__ float tile[32][33];
    const int tx = threadIdx.x, ty = threadIdx.y;
    const int m = blockIdx.x * 32 + tx;
    const int d0 = blockIdx.y * 32;
    for (int i = ty; i < 32; i += 8) {
        tile[i][tx] = (m < M_SIZE) ? W_m[(long)(d0 + i) * M_SIZE + m] : 0.0f;
    }
    __syncthreads();
    const int m0 = blockIdx.x * 32;
    for (int i = ty; i < 32; i += 8) {
        const int mm = m0 + i;
        if (mm < M_SIZE) W_mT[(long)mm * D_MODEL + d0 + tx] = tile[tx][i];
    }
}

// ---------------------------------------------------------------------------
// K2: bucket positive rows by marker. Entry = {s, bits(tv)}.
// Overflow (statistically impossible for uniform markers) -> direct slow write.
// ---------------------------------------------------------------------------
__global__ void bucket_kernel(const float* __restrict__ t,
                              const int* __restrict__ marker,
                              int* __restrict__ cnt,
                              int2* __restrict__ bkt,
                              const float* __restrict__ W_mT,
                              const float* __restrict__ W_t,
                              const float* __restrict__ b_t,
                              float* __restrict__ out) {
    const int s = blockIdx.x * 256 + threadIdx.x;
    if (s >= SEQ_LEN) return;
    const float tv = t[s];
    if (tv < 0.0f) return;
    const int m = marker[s];
    const int pos = atomicAdd(&cnt[m], 1);
    if (pos < CAP) {
        int2 e; e.x = s; e.y = __float_as_int(tv);
        bkt[m * CAP + pos] = e;
    } else {  // safety net, never expected
        const float* em = W_mT + (size_t)m * D_MODEL;
        for (int d = 0; d < D_MODEL; ++d)
            out[(size_t)s * D_MODEL + d] =
                BETA * em[d] + (1.0f - BETA) * fmaf(tv, W_t[d], b_t[d]);
    }
}

// ---------------------------------------------------------------------------
// K3 main. Blocks [0, 2000): bucket blocks — pair (m, h). The block reads its
// W_mT row ONCE (registers), precomputes base/slope, then streams full 2 KB
// rows: o = base + slope*tv. h splits the entry list (j parity) for balance.
// Blocks [2000, 2000+1024): zero-writers for t<0 rows.
// ---------------------------------------------------------------------------
#define NBKT_BLOCKS (M_SIZE * 2)
#define NZ_BLOCKS   1024
#define ZROWS       (SEQ_LEN / NZ_BLOCKS)   // 128

__global__ __launch_bounds__(256) void
embed_main(const float* __restrict__ t,
           const int* __restrict__ cnt,
           const int2* __restrict__ bkt,
           const float* __restrict__ W_mT,
           const float* __restrict__ W_t,
           const float* __restrict__ b_t,
           float* __restrict__ out) {
    f32x4* __restrict__ out4 = reinterpret_cast<f32x4*>(out);

    if (blockIdx.x < NBKT_BLOCKS) {
        const int m = blockIdx.x >> 1;
        const int h = blockIdx.x & 1;
        const int c = threadIdx.x & 127;   // float4 slot in row
        const int r = threadIdx.x >> 7;    // 0..1 (wave-pair)

        const f32x4 em = reinterpret_cast<const f32x4*>(W_mT + (size_t)m * D_MODEL)[c];
        const f32x4 w  = reinterpret_cast<const f32x4*>(W_t)[c];
        const f32x4 b  = reinterpret_cast<const f32x4*>(b_t)[c];
        const f32x4 base  = BETA * em + (1.0f - BETA) * b;
        const f32x4 slope = (1.0f - BETA) * w;

        const int n = min(cnt[m], CAP);
        const int2* __restrict__ bk = bkt + m * CAP;
        for (int j = h * 2 + r; j < n; j += 4) {
            const int2 e = bk[j];
            const float tv = __int_as_float(e.y);
            const f32x4 o = base + slope * tv;
            __builtin_nontemporal_store(o, out4 + (size_t)e.x * (D_MODEL / 4) + c);
        }
    } else {
        const int zb = (int)blockIdx.x - NBKT_BLOCKS;
        const int c = threadIdx.x & 127;
        const int rr = threadIdx.x >> 7;   // 0..1
        const int s0 = zb * ZROWS;
        const f32x4 z = (f32x4)(0.0f);
        for (int i = 0; i < ZROWS; i += 2) {
            const int s = s0 + i + rr;
            if (t[s] < 0.0f)
                __builtin_nontemporal_store(z, out4 + (size_t)s * (D_MODEL / 4) + c);
        }
    }
}

// ---------------------------------------------------------------------------
// Fallback if ws too small: direct gather (R3-style, known-correct ~57 us).
// ---------------------------------------------------------------------------
__global__ void embed_fallback(const float* __restrict__ t,
                               const int* __restrict__ marker,
                               const float* __restrict__ W_m,
                               const float* __restrict__ W_t,
                               const float* __restrict__ b_t,
                               float* __restrict__ out) {
    const long total4 = (long)SEQ_LEN * (D_MODEL / 4);
    const long stride = (long)gridDim.x * blockDim.x;
    for (long idx = (long)blockIdx.x * blockDim.x + threadIdx.x;
         idx < total4; idx += stride) {
        const int s = (int)(idx >> 7);
        const int c = (int)(idx & 127);
        const float tv = t[s];
        f32x4 o = (f32x4)(0.0f);
        if (tv >= 0.0f) {
            const int m = marker[s];
            const int d = c * 4;
            const f32x4 w = reinterpret_cast<const f32x4*>(W_t)[c];
            const f32x4 b = reinterpret_cast<const f32x4*>(b_t)[c];
            o.x = BETA * W_m[(long)(d + 0) * M_SIZE + m] + (1.0f - BETA) * fmaf(tv, w.x, b.x);
            o.y = BETA * W_m[(long)(d + 1) * M_SIZE + m] + (1.0f - BETA) * fmaf(tv, w.y, b.y);
            o.z = BETA * W_m[(long)(d + 2) * M_SIZE + m] + (1.0f - BETA) * fmaf(tv, w.z, b.z);
            o.w = BETA * W_m[(long)(d + 3) * M_SIZE + m] + (1.0f - BETA) * fmaf(tv, w.w, b.w);
        }
        reinterpret_cast<f32x4*>(out)[idx] = o;
    }
}

extern "C" void kernel_launch(void* const* d_in, const int* in_sizes, int n_in,
                              void* d_out, int out_size, void* d_ws, size_t ws_size,
                              hipStream_t stream) {
    const float* t      = (const float*)d_in[0];
    const int*   marker = (const int*)d_in[1];
    const float* W_m    = (const float*)d_in[2];
    const float* W_t    = (const float*)d_in[3];
    const float* b_t    = (const float*)d_in[4];
    float* out = (float*)d_out;

    if (ws_size < WS_NEED) {
        embed_fallback<<<2048, 256, 0, stream>>>(t, marker, W_m, W_t, b_t, out);
        return;
    }

    char* ws = (char*)d_ws;
    float* W_mT = (float*)(ws + WMT_OFF);
    int*   cnt  = (int*)(ws + CNT_OFF);
    int2*  bkt  = (int2*)(ws + BKT_OFF);

    dim3 tgrid((M_SIZE + 31) / 32, D_MODEL / 32);
    dim3 tblock(32, 8);
    transpose_wm_kernel<<<tgrid, tblock, 0, stream>>>(W_m, W_mT, cnt);

    bucket_kernel<<<SEQ_LEN / 256, 256, 0, stream>>>(t, marker, cnt, bkt,
                                                     W_mT, W_t, b_t, out);

    embed_main<<<NBKT_BLOCKS + NZ_BLOCKS, 256, 0, stream>>>(t, cnt, bkt,
                                                            W_mT, W_t, b_t, out);
}

// Round 7
// 59.439 us; speedup vs baseline: 1.3803x; 1.3803x over previous
//
#include <hip/hip_runtime.h>

#define SEQ_LEN 131072
#define D_MODEL 512
#define M_SIZE  1000
#define BETA    0.5f

typedef float f32x4 __attribute__((ext_vector_type(4)));
typedef unsigned short u16x4 __attribute__((ext_vector_type(4)));

__device__ inline unsigned short f32_to_bf16_rne(float f) {
    unsigned int u = __float_as_uint(f);
    u += 0x7fff + ((u >> 16) & 1);   // round-to-nearest-even
    return (unsigned short)(u >> 16);
}

// ---------------------------------------------------------------------------
// Prep: W_m [D][M] fp32 -> Tb [M][D] bf16 (1 MB). LDS-tiled transpose;
// reads coalesced along M, writes coalesced along D.
// ---------------------------------------------------------------------------
__global__ void build_table_kernel(const float* __restrict__ W_m,
                                   unsigned short* __restrict__ Tb) {
    __shared__ float tile[32][33];
    const int tx = threadIdx.x, ty = threadIdx.y;
    const int m = blockIdx.x * 32 + tx;
    const int d0 = blockIdx.y * 32;
    for (int i = ty; i < 32; i += 8) {
        tile[i][tx] = (m < M_SIZE) ? W_m[(long)(d0 + i) * M_SIZE + m] : 0.0f;
    }
    __syncthreads();
    const int m0 = blockIdx.x * 32;
    for (int i = ty; i < 32; i += 8) {
        const int mm = m0 + i;
        if (mm < M_SIZE)
            Tb[(size_t)mm * D_MODEL + d0 + tx] = f32_to_bf16_rne(tile[tx][i]);
    }
}

// ---------------------------------------------------------------------------
// Main. Thread owns fixed float4 slot c = tid&127, grid-strides rows
// (2048 blocks x 2 rows x 32 iters = 131072). Gather is 8 B/lane of bf16
// (wave = 512 B contiguous); converted to fp32 by <<16. No software
// pipeline (R4 showed it costs ~3 us at full TLP). NT stores.
// ---------------------------------------------------------------------------
__global__ __launch_bounds__(256) void
embed_kernel(const float* __restrict__ t,
             const int* __restrict__ marker,
             const unsigned short* __restrict__ Tb,
             const float* __restrict__ W_t,
             const float* __restrict__ b_t,
             float* __restrict__ out) {
    const int c = threadIdx.x & 127;          // float4 slot within row
    const int r = threadIdx.x >> 7;           // 0 or 1
    int s = (int)blockIdx.x * 2 + r;

    const f32x4 w = reinterpret_cast<const f32x4*>(W_t)[c];
    const f32x4 b = reinterpret_cast<const f32x4*>(b_t)[c];
    f32x4* __restrict__ out4 = reinterpret_cast<f32x4*>(out);

    for (int i = 0; i < 32; ++i, s += 4096) {
        const float tv = t[s];
        f32x4 o = (f32x4)(0.0f);
        if (tv >= 0.0f) {
            const int m = marker[s];
            const u16x4 e = *reinterpret_cast<const u16x4*>(
                Tb + (size_t)m * D_MODEL + c * 4);
            f32x4 em;
            em.x = __uint_as_float((unsigned)e.x << 16);
            em.y = __uint_as_float((unsigned)e.y << 16);
            em.z = __uint_as_float((unsigned)e.z << 16);
            em.w = __uint_as_float((unsigned)e.w << 16);
            o.x = BETA * em.x + (1.0f - BETA) * fmaf(tv, w.x, b.x);
            o.y = BETA * em.y + (1.0f - BETA) * fmaf(tv, w.y, b.y);
            o.z = BETA * em.z + (1.0f - BETA) * fmaf(tv, w.z, b.z);
            o.w = BETA * em.w + (1.0f - BETA) * fmaf(tv, w.w, b.w);
        }
        __builtin_nontemporal_store(o, out4 + (size_t)s * (D_MODEL / 4) + c);
    }
}

// ---------------------------------------------------------------------------
// Fallback (ws too small): direct fp32 column gather, known-correct.
// ---------------------------------------------------------------------------
__global__ void embed_fallback(const float* __restrict__ t,
                               const int* __restrict__ marker,
                               const float* __restrict__ W_m,
                               const float* __restrict__ W_t,
                               const float* __restrict__ b_t,
                               float* __restrict__ out) {
    const long total4 = (long)SEQ_LEN * (D_MODEL / 4);
    const long stride = (long)gridDim.x * blockDim.x;
    for (long idx = (long)blockIdx.x * blockDim.x + threadIdx.x;
         idx < total4; idx += stride) {
        const int s = (int)(idx >> 7);
        const int c = (int)(idx & 127);
        const float tv = t[s];
        f32x4 o = (f32x4)(0.0f);
        if (tv >= 0.0f) {
            const int m = marker[s];
            const int d = c * 4;
            const f32x4 w = reinterpret_cast<const f32x4*>(W_t)[c];
            const f32x4 b = reinterpret_cast<const f32x4*>(b_t)[c];
            o.x = BETA * W_m[(long)(d + 0) * M_SIZE + m] + (1.0f - BETA) * fmaf(tv, w.x, b.x);
            o.y = BETA * W_m[(long)(d + 1) * M_SIZE + m] + (1.0f - BETA) * fmaf(tv, w.y, b.y);
            o.z = BETA * W_m[(long)(d + 2) * M_SIZE + m] + (1.0f - BETA) * fmaf(tv, w.z, b.z);
            o.w = BETA * W_m[(long)(d + 3) * M_SIZE + m] + (1.0f - BETA) * fmaf(tv, w.w, b.w);
        }
        reinterpret_cast<f32x4*>(out)[idx] = o;
    }
}

extern "C" void kernel_launch(void* const* d_in, const int* in_sizes, int n_in,
                              void* d_out, int out_size, void* d_ws, size_t ws_size,
                              hipStream_t stream) {
    const float* t      = (const float*)d_in[0];
    const int*   marker = (const int*)d_in[1];
    const float* W_m    = (const float*)d_in[2];
    const float* W_t    = (const float*)d_in[3];
    const float* b_t    = (const float*)d_in[4];
    float* out = (float*)d_out;

    const size_t tb_bytes = (size_t)M_SIZE * D_MODEL * sizeof(unsigned short);  // 1 MB
    if (ws_size < tb_bytes) {
        embed_fallback<<<2048, 256, 0, stream>>>(t, marker, W_m, W_t, b_t, out);
        return;
    }

    unsigned short* Tb = (unsigned short*)d_ws;
    dim3 tgrid((M_SIZE + 31) / 32, D_MODEL / 32);  // 32 x 16
    dim3 tblock(32, 8);
    build_table_kernel<<<tgrid, tblock, 0, stream>>>(W_m, Tb);

    embed_kernel<<<2048, 256, 0, stream>>>(t, marker, Tb, W_t, b_t, out);
}

// Round 8
// 57.033 us; speedup vs baseline: 1.4386x; 1.0422x over previous
//
#include <hip/hip_runtime.h>

#define SEQ_LEN 131072
#define D_MODEL 512
#define M_SIZE  1000
#define BETA    0.5f

typedef float f32x4 __attribute__((ext_vector_type(4)));

// ---------------------------------------------------------------------------
// Transpose W_m [D_MODEL][M] -> W_mT [M][D_MODEL] (2 MB, L2-resident) so the
// per-row gather in the main kernel is contiguous float4 loads.
// ---------------------------------------------------------------------------
__global__ void transpose_wm_kernel(const float* __restrict__ W_m,
                                    float* __restrict__ W_mT) {
    __shared__ float tile[32][33];  // +1 pad: no LDS bank conflicts
    const int tx = threadIdx.x, ty = threadIdx.y;
    const int m = blockIdx.x * 32 + tx;
    const int d0 = blockIdx.y * 32;
    for (int i = ty; i < 32; i += 8) {
        tile[i][tx] = (m < M_SIZE) ? W_m[(long)(d0 + i) * M_SIZE + m] : 0.0f;
    }
    __syncthreads();
    const int m0 = blockIdx.x * 32;
    for (int i = ty; i < 32; i += 8) {
        const int mm = m0 + i;
        if (mm < M_SIZE) W_mT[(long)mm * D_MODEL + d0 + tx] = tile[tx][i];
    }
}

// ---------------------------------------------------------------------------
// Main kernel — the R1 configuration (best measured: 56.8 us).
// Flat grid-stride over S*128 float4s; cached (non-NT) stores; no software
// pipeline (R4 showed pipelining costs ~3 us at full TLP; R3 showed NT and
// fixed-c mapping are neutral). 2048 blocks x 256 threads = full TLP.
// ---------------------------------------------------------------------------
__global__ __launch_bounds__(256) void
embed_kernel(const float* __restrict__ t,
             const int* __restrict__ marker,
             const float* __restrict__ W_mT,
             const float* __restrict__ W_t,
             const float* __restrict__ b_t,
             float* __restrict__ out) {
    const long total4 = (long)SEQ_LEN * (D_MODEL / 4);  // 16,777,216
    const long stride = (long)gridDim.x * blockDim.x;
    for (long idx = (long)blockIdx.x * blockDim.x + threadIdx.x;
         idx < total4; idx += stride) {
        const int s = (int)(idx >> 7);        // row
        const int c = (int)(idx & 127);       // float4 slot within row
        const float tv = t[s];
        f32x4 o = (f32x4)(0.0f);
        if (tv >= 0.0f) {
            const int m = marker[s];
            const f32x4 em =
                reinterpret_cast<const f32x4*>(W_mT + (size_t)m * D_MODEL)[c];
            const f32x4 w = reinterpret_cast<const f32x4*>(W_t)[c];
            const f32x4 b = reinterpret_cast<const f32x4*>(b_t)[c];
            o.x = BETA * em.x + (1.0f - BETA) * fmaf(tv, w.x, b.x);
            o.y = BETA * em.y + (1.0f - BETA) * fmaf(tv, w.y, b.y);
            o.z = BETA * em.z + (1.0f - BETA) * fmaf(tv, w.z, b.z);
            o.w = BETA * em.w + (1.0f - BETA) * fmaf(tv, w.w, b.w);
        }
        reinterpret_cast<f32x4*>(out)[idx] = o;
    }
}

// ---------------------------------------------------------------------------
// Fallback (ws too small): direct fp32 column gather, known-correct.
// ---------------------------------------------------------------------------
__global__ void embed_fallback(const float* __restrict__ t,
                               const int* __restrict__ marker,
                               const float* __restrict__ W_m,
                               const float* __restrict__ W_t,
                               const float* __restrict__ b_t,
                               float* __restrict__ out) {
    const long total4 = (long)SEQ_LEN * (D_MODEL / 4);
    const long stride = (long)gridDim.x * blockDim.x;
    for (long idx = (long)blockIdx.x * blockDim.x + threadIdx.x;
         idx < total4; idx += stride) {
        const int s = (int)(idx >> 7);
        const int c = (int)(idx & 127);
        const float tv = t[s];
        f32x4 o = (f32x4)(0.0f);
        if (tv >= 0.0f) {
            const int m = marker[s];
            const int d = c * 4;
            const f32x4 w = reinterpret_cast<const f32x4*>(W_t)[c];
            const f32x4 b = reinterpret_cast<const f32x4*>(b_t)[c];
            o.x = BETA * W_m[(long)(d + 0) * M_SIZE + m] + (1.0f - BETA) * fmaf(tv, w.x, b.x);
            o.y = BETA * W_m[(long)(d + 1) * M_SIZE + m] + (1.0f - BETA) * fmaf(tv, w.y, b.y);
            o.z = BETA * W_m[(long)(d + 2) * M_SIZE + m] + (1.0f - BETA) * fmaf(tv, w.z, b.z);
            o.w = BETA * W_m[(long)(d + 3) * M_SIZE + m] + (1.0f - BETA) * fmaf(tv, w.w, b.w);
        }
        reinterpret_cast<f32x4*>(out)[idx] = o;
    }
}

extern "C" void kernel_launch(void* const* d_in, const int* in_sizes, int n_in,
                              void* d_out, int out_size, void* d_ws, size_t ws_size,
                              hipStream_t stream) {
    const float* t      = (const float*)d_in[0];
    const int*   marker = (const int*)d_in[1];
    const float* W_m    = (const float*)d_in[2];
    const float* W_t    = (const float*)d_in[3];
    const float* b_t    = (const float*)d_in[4];
    float* out = (float*)d_out;

    const size_t wmT_bytes = (size_t)M_SIZE * D_MODEL * sizeof(float);  // 2 MB
    if (ws_size < wmT_bytes) {
        embed_fallback<<<2048, 256, 0, stream>>>(t, marker, W_m, W_t, b_t, out);
        return;
    }

    float* W_mT = (float*)d_ws;
    dim3 tgrid((M_SIZE + 31) / 32, D_MODEL / 32);  // 32 x 16
    dim3 tblock(32, 8);
    transpose_wm_kernel<<<tgrid, tblock, 0, stream>>>(W_m, W_mT);

    embed_kernel<<<2048, 256, 0, stream>>>(t, marker, W_mT, W_t, b_t, out);
}